// Round 4
// baseline (360.711 us; speedup 1.0000x reference)
//
#include <hip/hip_runtime.h>
#include <math.h>

// CALayer: out = x * sigmoid(w2 @ leakyrelu(w1 @ mean(x,HW) + b1) + b2)
// B=8, C=256, H=W=128, Cs=16
#define Bn 8
#define Cn 256
#define CSn 16
#define HWn 16384
#define PL4 4096            // float4 per plane
#define NEG_SLOPE 0.2f
#define NPLANES (Bn * Cn)   // 2048

typedef float f4v __attribute__((ext_vector_type(4)));

// ws layout: [0]=counter(int), ws+64: y[2048], ws+64+2048: g[2048]
#define WS_Y_OFF 64
#define WS_G_OFF (64 + NPLANES)

// ---- Kernel 1: pool every plane; LAST block computes all 2048 gates --------
__global__ __launch_bounds__(256) void pool_gate_kernel(
    const float* __restrict__ x,  const float* __restrict__ w1,
    const float* __restrict__ b1, const float* __restrict__ w2,
    const float* __restrict__ b2, float* __restrict__ ws) {
    float* y = ws + WS_Y_OFF;
    float* g = ws + WS_G_OFF;
    int*  cnt = (int*)ws;
    const int bc = blockIdx.x;
    const int t  = threadIdx.x;

    // pool this plane
    const f4v* xp = (const f4v*)x + (size_t)bc * PL4;
    float sum = 0.f;
    #pragma unroll
    for (int i = 0; i < 16; ++i) {
        f4v v = xp[t + i * 256];
        sum += (v.x + v.y) + (v.z + v.w);
    }
    #pragma unroll
    for (int off = 32; off; off >>= 1)
        sum += __shfl_down(sum, off, 64);
    __shared__ float sm[4];
    __shared__ int last;
    if ((t & 63) == 0) sm[t >> 6] = sum;
    if (t == 0) last = 0;
    __syncthreads();
    if (t == 0) {
        y[bc] = (sm[0] + sm[1] + sm[2] + sm[3]) * (1.f / (float)HWn);
        __threadfence();                       // publish y before ticket
        int old = atomicAdd(cnt, 1);           // device-scope
        if (old == NPLANES - 1) last = 1;
    }
    __syncthreads();
    if (!last) return;

    // ---- last block: compute all gates ----
    __threadfence();                           // acquire: see all y[]
    __shared__ float ys[NPLANES];              // 8 KB
    __shared__ float y1s[Bn * CSn];            // 128 floats
    #pragma unroll
    for (int i = 0; i < NPLANES / 256; ++i)
        ys[t + i * 256] = y[t + i * 256];
    __syncthreads();
    if (t < Bn * CSn) {                        // 128 threads: y1[b][s]
        const int b = t >> 4, s = t & 15;
        float acc = b1[s];
        const float* wr = w1 + s * Cn;
        #pragma unroll 8
        for (int c = 0; c < Cn; ++c) acc += ys[b * Cn + c] * wr[c];
        y1s[t] = (acc >= 0.f) ? acc : NEG_SLOPE * acc;
    }
    __syncthreads();
    {                                          // 256 threads: c = t, 8 batches
        const int c = t;
        const f4v* w2c = (const f4v*)(w2 + c * CSn);
        f4v wv0 = w2c[0], wv1 = w2c[1], wv2 = w2c[2], wv3 = w2c[3];
        const float bias = b2[c];
        #pragma unroll
        for (int b = 0; b < Bn; ++b) {
            const float* yb = y1s + b * CSn;
            float a = bias;
            a += yb[0]*wv0.x + yb[1]*wv0.y + yb[2]*wv0.z + yb[3]*wv0.w;
            a += yb[4]*wv1.x + yb[5]*wv1.y + yb[6]*wv1.z + yb[7]*wv1.w;
            a += yb[8]*wv2.x + yb[9]*wv2.y + yb[10]*wv2.z + yb[11]*wv2.w;
            a += yb[12]*wv3.x + yb[13]*wv3.y + yb[14]*wv3.z + yb[15]*wv3.w;
            g[b * Cn + c] = 1.f / (1.f + __expf(-a));
        }
    }
}

// ---- Kernel 2: pure stream scale; reverse-group mapping for L2 hits --------
__global__ __launch_bounds__(256) void scale_kernel(const float* __restrict__ x,
                                                    const float* __restrict__ ws,
                                                    float* __restrict__ out) {
    const int blk = blockIdx.x;
    // reverse order in groups of 8: keeps plane%8 == blk%8 (XCD parity),
    // visits most-recently-pooled planes first (L2-hot)
    const int plane = (((NPLANES / 8 - 1) - (blk >> 3)) << 3) | (blk & 7);
    const float gval = ws[WS_G_OFF + plane];   // uniform → s_load
    const int t = threadIdx.x;
    const f4v* xp = (const f4v*)x + (size_t)plane * PL4;
    f4v* op = (f4v*)out + (size_t)plane * PL4;
    #pragma unroll
    for (int i = 0; i < 16; ++i) {
        f4v v = xp[t + i * 256];
        v *= gval;
        __builtin_nontemporal_store(v, &op[t + i * 256]);
    }
}

extern "C" void kernel_launch(void* const* d_in, const int* in_sizes, int n_in,
                              void* d_out, int out_size, void* d_ws, size_t ws_size,
                              hipStream_t stream) {
    const float* x  = (const float*)d_in[0];
    const float* w1 = (const float*)d_in[1];
    const float* b1 = (const float*)d_in[2];
    const float* w2 = (const float*)d_in[3];
    const float* b2 = (const float*)d_in[4];
    float* out = (float*)d_out;
    float* ws  = (float*)d_ws;

    hipMemsetAsync(d_ws, 0, 4, stream);        // zero the ticket counter
    pool_gate_kernel<<<NPLANES, 256, 0, stream>>>(x, w1, b1, w2, b2, ws);
    scale_kernel<<<NPLANES, 256, 0, stream>>>(x, ws, out);
}